// Round 6
// baseline (508.731 us; speedup 1.0000x reference)
//
#include <hip/hip_runtime.h>

#define N_NODES 50000
#define N_EDGES 800000
#define NBLKA 200                 // Phase-A blocks; 800000/200 = 4000 edges each
#define EPB (N_EDGES / NBLKA)     // 4000
#define NBUCK 196                 // ceil(50000/256) buckets of 256 nodes
#define MSCAN (256 * NBLKA)       // 51200 hist entries to scan

// ---------------------------------------------------------------------------
// Phase A1: per-block 256-bin histogram of dst>>8, bin-major global layout
__global__ void histA_kernel(const int* __restrict__ dst, int* __restrict__ hist) {
    __shared__ int h[256];
    h[threadIdx.x] = 0;
    __syncthreads();
    int base = blockIdx.x * EPB;
    for (int i = base + threadIdx.x; i < base + EPB; i += 256)
        atomicAdd(&h[dst[i] >> 8], 1);
    __syncthreads();
    hist[threadIdx.x * NBLKA + blockIdx.x] = h[threadIdx.x];
}

// ---------------------------------------------------------------------------
// Hierarchical exclusive scan (generic): in -> out (block-local), bsum per block
__global__ void scan1_kernel(const int* __restrict__ in, int* __restrict__ out,
                             int* __restrict__ bsum, int n) {
    __shared__ int s[256];
    int i = blockIdx.x * 256 + threadIdx.x;
    int v = (i < n) ? in[i] : 0;
    s[threadIdx.x] = v;
    __syncthreads();
    for (int d = 1; d < 256; d <<= 1) {
        int t = (threadIdx.x >= d) ? s[threadIdx.x - d] : 0;
        __syncthreads();
        s[threadIdx.x] += t;
        __syncthreads();
    }
    if (i < n) out[i] = s[threadIdx.x] - v;
    if (threadIdx.x == 255) bsum[blockIdx.x] = s[255];
}

__global__ void scan2_kernel(int* __restrict__ bsum, int* __restrict__ boff, int nb) {
    __shared__ int s[256];
    int t = threadIdx.x;
    int v = (t < nb) ? bsum[t] : 0;
    s[t] = v;
    __syncthreads();
    for (int d = 1; d < 256; d <<= 1) {
        int x = (t >= d) ? s[t - d] : 0;
        __syncthreads();
        s[t] += x;
        __syncthreads();
    }
    if (t < nb) boff[t] = s[t] - v;
    if (t == nb - 1) boff[nb] = s[t];
}

__global__ void scan3_kernel(int* __restrict__ out, const int* __restrict__ boff,
                             int n, int nb) {
    int i = blockIdx.x * 256 + threadIdx.x;
    if (i < n) out[i] += boff[blockIdx.x];
    if (i == n - 1) out[n] = boff[nb];
}

// ---------------------------------------------------------------------------
// Phase A2: scatter (src,dst) pairs to bucket-major ebuf using per-(block,bin)
// offsets from the scanned histogram. Runs are contiguous -> ~full-line writes.
__global__ void scatterA_kernel(const int* __restrict__ src, const int* __restrict__ dst,
                                const int* __restrict__ scanned, int2* __restrict__ ebuf) {
    __shared__ int off[256];
    off[threadIdx.x] = scanned[threadIdx.x * NBLKA + blockIdx.x];
    __syncthreads();
    int base = blockIdx.x * EPB;
    for (int i = base + threadIdx.x; i < base + EPB; i += 256) {
        int s = src[i];
        int d = dst[i];
        int p = atomicAdd(&off[d >> 8], 1);
        ebuf[p] = make_int2(s, d);
    }
}

// ---------------------------------------------------------------------------
// Phase B: one block per 256-node bucket. Counts per-node degree in LDS,
// LDS-scan -> rowstart + dinv, then LDS-cursor scatter of esrc (no global
// atomics; each bucket's esrc region is written by exactly one block).
__global__ void bucket_kernel(const int2* __restrict__ ebuf, const int* __restrict__ scanned,
                              int* __restrict__ rowstart, float* __restrict__ dinv,
                              int* __restrict__ esrc) {
    __shared__ int cnt[256];
    __shared__ int cur[256];
    __shared__ int s[256];
    int k = blockIdx.x;
    int tid = threadIdx.x;
    int base = scanned[k * NBLKA];
    int end  = scanned[(k + 1) * NBLKA];
    cnt[tid] = 0;
    __syncthreads();
    for (int i = base + tid; i < end; i += 256)
        atomicAdd(&cnt[ebuf[i].y & 255], 1);
    __syncthreads();
    int v = cnt[tid];
    s[tid] = v;
    __syncthreads();
    for (int d = 1; d < 256; d <<= 1) {
        int t = (tid >= d) ? s[tid - d] : 0;
        __syncthreads();
        s[tid] += t;
        __syncthreads();
    }
    int excl = s[tid] - v;
    int node = (k << 8) + tid;
    cur[tid] = base + excl;
    if (node < N_NODES) {
        rowstart[node] = base + excl;
        dinv[node] = rsqrtf((float)v + 1.0f);
    }
    if (k == 0 && tid == 0) rowstart[N_NODES] = N_EDGES;
    __syncthreads();
    for (int i = base + tid; i < end; i += 256) {
        int2 e = ebuf[i];
        int p = atomicAdd(&cur[e.y & 255], 1);
        esrc[p] = e.x;
    }
}

// ---------------------------------------------------------------------------
// W12 = W1 @ W2 (96x96 @ 96x64), bw = b1 @ W2
__global__ void wfuse_kernel(const float* __restrict__ W1, const float* __restrict__ W2,
                             const float* __restrict__ b1, float* __restrict__ W12,
                             float* __restrict__ bw) {
    int idx = blockIdx.x * blockDim.x + threadIdx.x;
    if (idx < 96 * 64) {
        int k = idx >> 6, nn = idx & 63;
        float s = 0.0f;
#pragma unroll
        for (int j = 0; j < 96; ++j) s = fmaf(W1[k * 96 + j], W2[j * 64 + nn], s);
        W12[idx] = s;
    } else if (idx < 96 * 64 + 64) {
        int nn = idx - 96 * 64;
        float s = 0.0f;
#pragma unroll
        for (int j = 0; j < 96; ++j) s = fmaf(b1[j], W2[j * 64 + nn], s);
        bw[nn] = s;
    }
}

// ---------------------------------------------------------------------------
// y[M,64] = A[M,96] @ W[96,64]. Register-tiled, LDS-only inner loop:
// 64-row x 64-col block tile, 16x16 threads, 4x4 outputs/thread, K=96 staged.
// sA padded to stride 100 (16B-aligned, <=2-way bank aliasing = free).
__global__ void gemm_kernel(const float* __restrict__ A, const float* __restrict__ W,
                            float* __restrict__ out, int M) {
    __shared__ float sW[96 * 64];     // [k][col]
    __shared__ float sA[64 * 100];    // [row][k], padded
    int tid = threadIdx.x;

    {   // stage W (coalesced float4)
        const float4* W4 = (const float4*)W;
        float4* sW4 = (float4*)sW;
        for (int i = tid; i < 96 * 16; i += 256) sW4[i] = W4[i];
    }
    long row0 = (long)blockIdx.x * 64;
    {   // stage A rows [row0, row0+64) (coalesced float4; clamp for tail block)
        const float4* A4 = (const float4*)A;
        long base4 = row0 * 24;                       // row0*96/4
        long lim = (long)M * 24 - 1;
        for (int f = tid; f < 64 * 24; f += 256) {
            long g = base4 + f;
            if (g > lim) g = lim;
            float4 v = A4[g];
            int r = f / 24, kc = f - r * 24;
            *(float4*)(sA + r * 100 + kc * 4) = v;
        }
    }
    __syncthreads();

    int tx = tid & 15;        // col group: cols tx*4 .. tx*4+3
    int ty = tid >> 4;        // row group: rows ty*4 .. ty*4+3
    float acc[4][4] = {};
    const float* pa = sA + ty * 4 * 100;

#pragma unroll
    for (int k = 0; k < 96; k += 4) {
        float4 a0 = *(const float4*)(pa + 0 * 100 + k);
        float4 a1 = *(const float4*)(pa + 1 * 100 + k);
        float4 a2 = *(const float4*)(pa + 2 * 100 + k);
        float4 a3 = *(const float4*)(pa + 3 * 100 + k);
        float4 w0 = *(const float4*)(sW + (k + 0) * 64 + tx * 4);
        float4 w1 = *(const float4*)(sW + (k + 1) * 64 + tx * 4);
        float4 w2 = *(const float4*)(sW + (k + 2) * 64 + tx * 4);
        float4 w3 = *(const float4*)(sW + (k + 3) * 64 + tx * 4);
        const float4 av[4] = {a0, a1, a2, a3};
#pragma unroll
        for (int i = 0; i < 4; ++i) {
            acc[i][0] = fmaf(av[i].x, w0.x, acc[i][0]);
            acc[i][1] = fmaf(av[i].x, w0.y, acc[i][1]);
            acc[i][2] = fmaf(av[i].x, w0.z, acc[i][2]);
            acc[i][3] = fmaf(av[i].x, w0.w, acc[i][3]);
            acc[i][0] = fmaf(av[i].y, w1.x, acc[i][0]);
            acc[i][1] = fmaf(av[i].y, w1.y, acc[i][1]);
            acc[i][2] = fmaf(av[i].y, w1.z, acc[i][2]);
            acc[i][3] = fmaf(av[i].y, w1.w, acc[i][3]);
            acc[i][0] = fmaf(av[i].z, w2.x, acc[i][0]);
            acc[i][1] = fmaf(av[i].z, w2.y, acc[i][1]);
            acc[i][2] = fmaf(av[i].z, w2.z, acc[i][2]);
            acc[i][3] = fmaf(av[i].z, w2.w, acc[i][3]);
            acc[i][0] = fmaf(av[i].w, w3.x, acc[i][0]);
            acc[i][1] = fmaf(av[i].w, w3.y, acc[i][1]);
            acc[i][2] = fmaf(av[i].w, w3.z, acc[i][2]);
            acc[i][3] = fmaf(av[i].w, w3.w, acc[i][3]);
        }
    }

#pragma unroll
    for (int i = 0; i < 4; ++i) {
        long r = row0 + ty * 4 + i;
        if (r < M) {
            float4 v = make_float4(acc[i][0], acc[i][1], acc[i][2], acc[i][3]);
            *(float4*)(out + r * 64 + tx * 4) = v;
        }
    }
}

// ---------------------------------------------------------------------------
// One 64-lane wave per node:
//   out[i,:] = di^2*y[i,:] + di * sum_e dinv[src_e]*y[src_e,:]   (+ FINAL bias)
template <bool FINAL>
__global__ void agg_kernel(const float* __restrict__ y, const int* __restrict__ rowstart,
                           const int* __restrict__ esrc, const float* __restrict__ dinv,
                           const float* __restrict__ bw, const float* __restrict__ b2,
                           float* __restrict__ out, int n) {
    int wid = (blockIdx.x * blockDim.x + threadIdx.x) >> 6;
    int lane = threadIdx.x & 63;
    if (wid >= n) return;
    int rs = rowstart[wid];
    int re = rowstart[wid + 1];
    float di = dinv[wid];
    float self = y[(long)wid * 64 + lane];
    float a0 = 0.0f, a1 = 0.0f, a2 = 0.0f, a3 = 0.0f;
    float sd = 0.0f;
    for (int base = rs; base < re; base += 64) {
        int idx = base + lane;
        bool ok = idx < re;
        int sj = ok ? esrc[idx] : 0;
        float dj = ok ? dinv[sj] : 0.0f;
        sd += dj;
        int nn = min(64, re - base);
        int j = 0;
        for (; j + 4 <= nn; j += 4) {
            int s0 = __shfl(sj, j + 0); float c0 = __shfl(dj, j + 0);
            int s1 = __shfl(sj, j + 1); float c1 = __shfl(dj, j + 1);
            int s2 = __shfl(sj, j + 2); float c2 = __shfl(dj, j + 2);
            int s3 = __shfl(sj, j + 3); float c3 = __shfl(dj, j + 3);
            float v0 = y[(long)s0 * 64 + lane];
            float v1 = y[(long)s1 * 64 + lane];
            float v2 = y[(long)s2 * 64 + lane];
            float v3 = y[(long)s3 * 64 + lane];
            a0 = fmaf(v0, c0, a0);
            a1 = fmaf(v1, c1, a1);
            a2 = fmaf(v2, c2, a2);
            a3 = fmaf(v3, c3, a3);
        }
        for (; j < nn; ++j) {
            int s0 = __shfl(sj, j); float c0 = __shfl(dj, j);
            a0 = fmaf(y[(long)s0 * 64 + lane], c0, a0);
        }
    }
    float acc = fmaf((a0 + a1) + (a2 + a3), di, self * di * di);
    if (FINAL) {
#pragma unroll
        for (int m = 1; m < 64; m <<= 1) sd += __shfl_xor(sd, m);
        float si = di * (di + sd);
        acc = fmaf(si, bw[lane], acc) + b2[lane];
    }
    out[(long)wid * 64 + lane] = acc;
}

// ---------------------------------------------------------------------------
extern "C" void kernel_launch(void* const* d_in, const int* in_sizes, int n_in,
                              void* d_out, int out_size, void* d_ws, size_t ws_size,
                              hipStream_t stream) {
    const float* x  = (const float*)d_in[0];
    const int*   ei = (const int*)d_in[1];
    const float* W1 = (const float*)d_in[2];
    const float* b1 = (const float*)d_in[3];
    const float* W2 = (const float*)d_in[4];
    const float* b2 = (const float*)d_in[5];
    float* out = (float*)d_out;

    const int* src = ei;
    const int* dst = ei + N_EDGES;

    // workspace layout (bytes); ebuf aliases z (disjoint lifetimes)
    char* ws = (char*)d_ws;
    float* dinv     = (float*)(ws + 0);                  // 204800
    int*   rowstart = (int*)  (ws + 204800);             // 200004 -> pad 204800
    int*   hist     = (int*)  (ws + 409600);             // 204800 (51200 ints)
    int*   scanned  = (int*)  (ws + 614400);             // 204804 -> pad 208896
    int*   bsum     = (int*)  (ws + 823296);             // 1024
    int*   boff     = (int*)  (ws + 824320);             // 1024
    float* W12      = (float*)(ws + 825344);             // 24576
    float* bw       = (float*)(ws + 849920);             // 512
    int*   esrc     = (int*)  (ws + 850432);             // 3200000
    float* y        = (float*)(ws + 4050432);            // 12800000
    int2*  ebuf     = (int2*) (ws + 16850432);           // 6400000 (aliases z)
    float* z        = (float*)(ws + 16850432);           // 12800000 (end 29.65MB)

    // Phase A: bucket edges by dst>>8 with full-line writes
    histA_kernel<<<NBLKA, 256, 0, stream>>>(dst, hist);
    scan1_kernel<<<MSCAN / 256, 256, 0, stream>>>(hist, scanned, bsum, MSCAN);
    scan2_kernel<<<1, 256, 0, stream>>>(bsum, boff, MSCAN / 256);
    scan3_kernel<<<MSCAN / 256, 256, 0, stream>>>(scanned, boff, MSCAN, MSCAN / 256);
    scatterA_kernel<<<NBLKA, 256, 0, stream>>>(src, dst, scanned, ebuf);

    // Phase B: per-bucket degree count + rowstart + dinv + LDS-cursor scatter
    bucket_kernel<<<NBUCK, 256, 0, stream>>>(ebuf, scanned, rowstart, dinv, esrc);

    // fused weights + single GEMM
    wfuse_kernel<<<(96 * 64 + 64 + 255) / 256, 256, 0, stream>>>(W1, W2, b1, W12, bw);
    gemm_kernel<<<(N_NODES + 63) / 64, 256, 0, stream>>>(x, W12, y, N_NODES);

    // two aggregation passes: z = N y ; out = N z + s*bw + b2
    int aggBlocks = (N_NODES + 3) / 4;  // one 64-lane wave per node, 4 waves/block
    agg_kernel<false><<<aggBlocks, 256, 0, stream>>>(y, rowstart, esrc, dinv, bw, b2, z, N_NODES);
    agg_kernel<true><<<aggBlocks, 256, 0, stream>>>(z, rowstart, esrc, dinv, bw, b2, out, N_NODES);
}